// Round 17
// baseline (32.642 us; speedup 1.0000x reference)
//
#include <hip/hip_runtime.h>

#define DIM 120
#define NB 16            // batch rows per block
#define NBP 20           // padded LDS stride in dwords (b128-aligned)
#define BLOCK 512        // one thread per output row; 2KB span per (block,b)
#define NG (NB / 4)      // float4 groups along b
#define NXCD 8
#define SMEM_FLOATS (2 * DIM * NBP)   // 4800 floats = 19.2 KB (>= 16 KB half-exchange)

typedef float f32x4 __attribute__((ext_vector_type(4)));   // nt-store-legal vec4

// ---- Fused preprocess: diff-based CSR row pointers + packed entries ----
__global__ void pre_kernel(const int* __restrict__ oi, int K, int H,
                           int* __restrict__ row_start,
                           const int* __restrict__ i1, const int* __restrict__ i2,
                           const int* __restrict__ cb, const float* __restrict__ pal,
                           uint2* __restrict__ ent) {
    int k = blockIdx.x * blockDim.x + threadIdx.x;
    if (k < K) {
        uint2 e;
        e.x = (unsigned)i1[k] | ((unsigned)i2[k] << 16);
        e.y = __float_as_uint(pal[cb[k]]);
        ent[k] = e;
        const int cur = oi[k];
        const int prev = (k == 0) ? -1 : oi[k - 1];
        for (int o = prev + 1; o <= cur; ++o) row_start[o] = k;
    } else if (k == K) {
        const int prev = oi[K - 1];
        for (int o = prev + 1; o <= H; ++o) row_start[o] = K;
    }
}

// ---- Main: R16 structure at BLOCK=512; exchange in 2 rounds of 8 b-rows ----
__global__ __launch_bounds__(BLOCK, 8) void tp_kernel(
    const float* __restrict__ in1, const float* __restrict__ in2,
    const uint2* __restrict__ ent, const int* __restrict__ row_start,
    float* __restrict__ out, int H, int nbx) {
    // bijective XCD-chunked swizzle over the o-block dimension
    int x = blockIdx.x;
    {
        const int q = nbx / NXCD, r = nbx % NXCD;
        const int xcd = x % NXCD, pos = x / NXCD;
        x = (xcd < r) ? (xcd * (q + 1) + pos) : (r * (q + 1) + (xcd - r) * q + pos);
    }

    __shared__ __align__(16) float smem[SMEM_FLOATS];
    float* __restrict__ s1t = smem;
    float* __restrict__ s2t = smem + DIM * NBP;

    // --- stage NB batch-rows transposed to [d][b] (960 cells, 2 iters) ---
    const int b0 = blockIdx.y * NB;
    for (int t = threadIdx.x; t < 2 * DIM * NG; t += BLOCK) {
        const int arr = (t >= DIM * NG);
        const int c = arr ? t - DIM * NG : t;
        const int d = c % DIM;
        const int g = c / DIM;
        const float* __restrict__ src = arr ? in2 : in1;
        const size_t base = (size_t)(b0 + 4 * g) * DIM + d;
        float4 v;
        v.x = src[base + 0 * DIM];
        v.y = src[base + 1 * DIM];
        v.z = src[base + 2 * DIM];
        v.w = src[base + 3 * DIM];
        float* dst = arr ? s2t : s1t;
        *(float4*)(dst + d * NBP + 4 * g) = v;
    }
    __syncthreads();

    const int o0 = x * BLOCK;
    const int o = o0 + (int)threadIdx.x;
    const bool act = (o < H);

    float acc[NB];
#pragma unroll
    for (int b = 0; b < NB; ++b) acc[b] = 0.0f;

    if (act) {
        const int k0 = row_start[o];
        const int k1 = row_start[o + 1];
        for (int k = k0; k < k1; ++k) {
            const uint2 e = ent[k];
            const float4* __restrict__ pa = (const float4*)(s1t + (e.x & 0xffffu) * NBP);
            const float4* __restrict__ pc = (const float4*)(s2t + (e.x >> 16) * NBP);
            const float v = __uint_as_float(e.y);
#pragma unroll
            for (int j = 0; j < NG; ++j) {
                const float4 x4 = pa[j];
                const float4 y4 = pc[j];
                acc[4 * j + 0] = fmaf(v * x4.x, y4.x, acc[4 * j + 0]);
                acc[4 * j + 1] = fmaf(v * x4.y, y4.y, acc[4 * j + 1]);
                acc[4 * j + 2] = fmaf(v * x4.z, y4.z, acc[4 * j + 2]);
                acc[4 * j + 3] = fmaf(v * x4.w, y4.w, acc[4 * j + 3]);
            }
        }
    }
    __syncthreads();   // staging reads complete before overwriting smem

    if (o0 + BLOCK <= H) {
        const int wave = threadIdx.x >> 6;   // 0..7
        const int lane = threadIdx.x & 63;
#pragma unroll
        for (int r = 0; r < 2; ++r) {
            // exchange round r: b-rows r*8 .. r*8+7 -> smem[bl][512], stride-1
#pragma unroll
            for (int j = 0; j < 8; ++j)
                smem[j * BLOCK + threadIdx.x] = acc[r * 8 + j];
            __syncthreads();
            // wave w owns b-local = w: 512 floats = 2 back-to-back 1KB NT bursts
            const int b = b0 + r * 8 + wave;
            f32x4 v0 = *(const f32x4*)(smem + wave * BLOCK + 0 * 256 + 4 * lane);
            f32x4 v1 = *(const f32x4*)(smem + wave * BLOCK + 1 * 256 + 4 * lane);
            __builtin_nontemporal_store(
                v0, (f32x4*)(out + (size_t)b * H + o0 + 0 * 256 + 4 * lane));
            __builtin_nontemporal_store(
                v1, (f32x4*)(out + (size_t)b * H + o0 + 1 * 256 + 4 * lane));
            __syncthreads();   // stores' source reads done before next round's writes
        }
    } else if (act) {
        // partial last tile: per-thread scalar nt stores
#pragma unroll
        for (int b = 0; b < NB; ++b)
            __builtin_nontemporal_store(acc[b], &out[(size_t)(b0 + b) * H + o]);
    }
}

extern "C" void kernel_launch(void* const* d_in, const int* in_sizes, int n_in,
                              void* d_out, int out_size, void* d_ws, size_t ws_size,
                              hipStream_t stream) {
    const float* in1 = (const float*)d_in[0];
    const float* in2 = (const float*)d_in[1];
    const float* pal = (const float*)d_in[2];
    const int*   i1  = (const int*)d_in[3];
    const int*   i2  = (const int*)d_in[4];
    const int*   oi  = (const int*)d_in[5];
    const int*   cb  = (const int*)d_in[6];

    const int K = in_sizes[3];
    const int B = in_sizes[0] / DIM;   // 2048
    const int H = out_size / B;        // 14400

    uint2* ent = (uint2*)d_ws;
    int* row_start = (int*)((char*)d_ws + (size_t)K * sizeof(uint2));

    pre_kernel<<<(K + 1 + 255) / 256, 256, 0, stream>>>(oi, K, H, row_start,
                                                        i1, i2, cb, pal, ent);

    const int nbx = (H + BLOCK - 1) / BLOCK;   // 29
    dim3 grid(nbx, B / NB);
    tp_kernel<<<grid, BLOCK, 0, stream>>>(in1, in2, ent, row_start,
                                          (float*)d_out, H, nbx);
}